// Round 1
// baseline (2805.586 us; speedup 1.0000x reference)
//
#include <hip/hip_runtime.h>

typedef __attribute__((ext_vector_type(8))) unsigned short ushort8v;
typedef __attribute__((ext_vector_type(8))) short short8v;
typedef __attribute__((ext_vector_type(4))) float f32x4;

__device__ inline unsigned short f2bf(float f) {
    union { float f; unsigned u; } v; v.f = f;
    unsigned u = v.u;
    unsigned r = (u + 0x7FFFu + ((u >> 16) & 1u)) >> 16;
    return (unsigned short)r;
}
__device__ inline float bf2f(unsigned short h) {
    union { unsigned u; float f; } v; v.u = ((unsigned)h) << 16;
    return v.f;
}

// ---------------------------------------------------------------------------
// Weight prep: W1t[jj][k] (256x128 bf16) so AB = feat @ [W1_top | W1_bot];
// W3t[n][k]  (128x256 bf16) so out = [S | feat] @ [W2 ; LW].
// Both stored transposed (N x K) so MFMA B-fragment loads are contiguous in k.
// ---------------------------------------------------------------------------
__global__ void prep_weights(const float* __restrict__ W1, const float* __restrict__ W2,
                             const float* __restrict__ LW,
                             unsigned short* __restrict__ W1t,
                             unsigned short* __restrict__ W3t) {
    int i = blockIdx.x * 256 + threadIdx.x;  // 0..65535
    if (i < 32768) {
        int jj = i >> 7, k = i & 127;
        float v = (jj < 128) ? W1[k * 128 + jj] : W1[(128 + k) * 128 + (jj - 128)];
        W1t[i] = f2bf(v);
    } else {
        int i2 = i - 32768;
        int n = i2 >> 8, k = i2 & 255;
        float v = (k < 128) ? W2[k * 128 + n] : LW[(k - 128) * 128 + n];
        W3t[i2] = f2bf(v);
    }
}

// feat (f32 [N,128]) -> X2 cols 128..255 (bf16, row stride 256)
__global__ void feat_to_bf16(const float* __restrict__ feat,
                             unsigned short* __restrict__ X2, int total) {
    int idx = (blockIdx.x * 256 + threadIdx.x) * 4;
    if (idx >= total) return;
    float4 v = *(const float4*)(feat + idx);
    int row = idx >> 7, col = idx & 127;
    unsigned short* o = X2 + (size_t)row * 256 + 128 + col;
    ushort4 u = make_ushort4(f2bf(v.x), f2bf(v.y), f2bf(v.z), f2bf(v.w));
    *(ushort4*)o = u;
}

// S (f32 [N,128]) -> X2 cols 0..127 (bf16)
__global__ void s_to_bf16(const float* __restrict__ S,
                          unsigned short* __restrict__ X2, int total) {
    int idx = (blockIdx.x * 256 + threadIdx.x) * 4;
    if (idx >= total) return;
    float4 v = *(const float4*)(S + idx);
    int row = idx >> 7, col = idx & 127;
    unsigned short* o = X2 + (size_t)row * 256 + col;
    ushort4 u = make_ushort4(f2bf(v.x), f2bf(v.y), f2bf(v.z), f2bf(v.w));
    *(ushort4*)o = u;
}

// ---------------------------------------------------------------------------
// 128x128-tile bf16 MFMA GEMM: C[m,n] = sum_k A[m,k] * Bt[n,k]  (+ bias[n])
// A row-major (lda), Bt row-major (ldb, i.e. B stored N x K).
// XOR-swizzled LDS (16B blocks, blk ^ (row&15)) -> 2-way max bank aliasing.
// 256 threads = 4 waves in 2x2; each wave does 4x4 tiles of 16x16x32 MFMA.
// ---------------------------------------------------------------------------
template <bool OUT_BF16>
__global__ __launch_bounds__(256) void gemm128(
    const unsigned short* __restrict__ A, int lda,
    const unsigned short* __restrict__ Bt, int ldb, int nRowsB,
    void* __restrict__ Cout, int ldc,
    const float* __restrict__ bias, int M, int K) {
    __shared__ unsigned short As[128 * 128];
    __shared__ unsigned short Bs[128 * 128];
    const int tid = threadIdx.x;
    const int m0 = blockIdx.x * 128;
    const int n0 = blockIdx.y * 128;
    const int lane = tid & 63;
    const int w = tid >> 6;
    const int wr = w >> 1, wc = w & 1;
    const int q = lane >> 4, ln = lane & 15;

    f32x4 acc[4][4];
#pragma unroll
    for (int i = 0; i < 4; i++)
#pragma unroll
        for (int j = 0; j < 4; j++) acc[i][j] = (f32x4)0.f;

    for (int kk = 0; kk < K; kk += 128) {
#pragma unroll
        for (int i = 0; i < 8; i++) {   // stage A tile
            int id = i * 256 + tid;
            int r = id >> 4, b = id & 15;
            ushort8v v = (ushort8v)(unsigned short)0;
            int gr = m0 + r;
            if (gr < M) v = *(const ushort8v*)(A + (size_t)gr * lda + kk + b * 8);
            *(ushort8v*)(As + r * 128 + ((b ^ (r & 15)) * 8)) = v;
        }
#pragma unroll
        for (int i = 0; i < 8; i++) {   // stage Bt tile
            int id = i * 256 + tid;
            int r = id >> 4, b = id & 15;
            ushort8v v = (ushort8v)(unsigned short)0;
            int gr = n0 + r;
            if (gr < nRowsB) v = *(const ushort8v*)(Bt + (size_t)gr * ldb + kk + b * 8);
            *(ushort8v*)(Bs + r * 128 + ((b ^ (r & 15)) * 8)) = v;
        }
        __syncthreads();
#pragma unroll
        for (int ks = 0; ks < 4; ks++) {
            short8v af[4], bfv[4];
#pragma unroll
            for (int ti = 0; ti < 4; ti++) {
                int m = wr * 64 + ti * 16 + ln;
                int blk = (ks * 4 + q) ^ (m & 15);
                af[ti] = *(const short8v*)(As + m * 128 + blk * 8);
            }
#pragma unroll
            for (int tj = 0; tj < 4; tj++) {
                int n = wc * 64 + tj * 16 + ln;
                int blk = (ks * 4 + q) ^ (n & 15);
                bfv[tj] = *(const short8v*)(Bs + n * 128 + blk * 8);
            }
#pragma unroll
            for (int ti = 0; ti < 4; ti++)
#pragma unroll
                for (int tj = 0; tj < 4; tj++)
                    acc[ti][tj] = __builtin_amdgcn_mfma_f32_16x16x32_bf16(
                        af[ti], bfv[tj], acc[ti][tj], 0, 0, 0);
        }
        __syncthreads();
    }

    // Epilogue: C/D layout col = lane&15, row = quad*4 + reg (m89/m91 verified)
#pragma unroll
    for (int ti = 0; ti < 4; ti++) {
        int rowb = m0 + wr * 64 + ti * 16 + q * 4;
#pragma unroll
        for (int tj = 0; tj < 4; tj++) {
            int col = n0 + wc * 64 + tj * 16 + ln;
            f32x4 c = acc[ti][tj];
            float bv = 0.f;
            if (!OUT_BF16 && bias) bv = bias[col];
#pragma unroll
            for (int r = 0; r < 4; r++) {
                int row = rowb + r;
                if (row < M) {
                    if (OUT_BF16)
                        ((unsigned short*)Cout)[(size_t)row * ldc + col] = f2bf(c[r]);
                    else
                        ((float*)Cout)[(size_t)row * ldc + col] = c[r] + bv;
                }
            }
        }
    }
}

// ---------------------------------------------------------------------------
// Edge pass: S[dst] += relu(A[src] + B[dst]); AB row = [A | B] bf16, 256 wide.
// 8 threads per edge, 16 channels each. Atomic skipped when relu output is 0.
// ---------------------------------------------------------------------------
__global__ __launch_bounds__(256) void edge_pass(
    const unsigned short* __restrict__ AB, const int* __restrict__ src,
    const int* __restrict__ dst, float* __restrict__ S, int E) {
    int t = blockIdx.x * 256 + threadIdx.x;
    int e = t >> 3;
    if (e >= E) return;
    int part = t & 7;
    int s = src[e], d = dst[e];
    const unsigned short* arow = AB + (size_t)s * 256 + part * 16;
    const unsigned short* brow = AB + (size_t)d * 256 + 128 + part * 16;
    ushort8v a0 = *(const ushort8v*)(arow);
    ushort8v a1 = *(const ushort8v*)(arow + 8);
    ushort8v b0 = *(const ushort8v*)(brow);
    ushort8v b1 = *(const ushort8v*)(brow + 8);
    float* o = S + (size_t)d * 128 + part * 16;
#pragma unroll
    for (int i = 0; i < 8; i++) {
        float x = bf2f(a0[i]) + bf2f(b0[i]);
        if (x > 0.f) unsafeAtomicAdd(o + i, x);
        float y = bf2f(a1[i]) + bf2f(b1[i]);
        if (y > 0.f) unsafeAtomicAdd(o + 8 + i, y);
    }
}

// ---------------------------------------------------------------------------
extern "C" void kernel_launch(void* const* d_in, const int* in_sizes, int n_in,
                              void* d_out, int out_size, void* d_ws, size_t ws_size,
                              hipStream_t stream) {
    const float* feat = (const float*)d_in[0];
    const int* src = (const int*)d_in[1];
    const int* dst = (const int*)d_in[2];
    const float* W1 = (const float*)d_in[3];
    const float* W2 = (const float*)d_in[4];
    const float* LW = (const float*)d_in[5];
    const float* bias = (const float*)d_in[6];
    float* out = (float*)d_out;

    const int N = in_sizes[0] / 128;  // 50000
    const int E = in_sizes[1];        // 800000

    char* ws = (char*)d_ws;
    unsigned short* X2 = (unsigned short*)ws;          // [N,256] bf16: cols0-127=S, 128-255=feat
    size_t off = (size_t)N * 256 * 2;
    unsigned short* AB = (unsigned short*)(ws + off);  // [N,256] bf16: cols0-127=A, 128-255=B
    off += (size_t)N * 256 * 2;
    float* S = (float*)(ws + off);                     // [N,128] f32 accumulator
    off += (size_t)N * 128 * 4;
    unsigned short* W1t = (unsigned short*)(ws + off); // [256,128] bf16
    off += (size_t)256 * 128 * 2;
    unsigned short* W3t = (unsigned short*)(ws + off); // [128,256] bf16
    off += (size_t)128 * 256 * 2;

    hipMemsetAsync(S, 0, (size_t)N * 128 * 4, stream);
    prep_weights<<<256, 256, 0, stream>>>(W1, W2, LW, W1t, W3t);

    int totalF = N * 128;
    int cvtBlocks = (totalF / 4 + 255) / 256;
    feat_to_bf16<<<cvtBlocks, 256, 0, stream>>>(feat, X2, totalF);

    dim3 g1((N + 127) / 128, 2);
    gemm128<true><<<g1, 256, 0, stream>>>(X2 + 128, 256, W1t, 128, 256,
                                          (void*)AB, 256, nullptr, N, 128);

    long long eThreads = (long long)E * 8;
    edge_pass<<<(int)((eThreads + 255) / 256), 256, 0, stream>>>(AB, src, dst, S, E);

    s_to_bf16<<<cvtBlocks, 256, 0, stream>>>(S, X2, totalF);

    dim3 g2((N + 127) / 128, 1);
    gemm128<false><<<g2, 256, 0, stream>>>(X2, 256, W3t, 256, 128,
                                           (void*)out, 128, bias, N, 256);
}

// Round 2
// 257.786 us; speedup vs baseline: 10.8834x; 10.8834x over previous
//
#include <hip/hip_runtime.h>

typedef __attribute__((ext_vector_type(8))) unsigned short ushort8v;
typedef __attribute__((ext_vector_type(8))) short short8v;
typedef __attribute__((ext_vector_type(4))) float f32x4;

__device__ inline unsigned short f2bf(float f) {
    union { float f; unsigned u; } v; v.f = f;
    unsigned u = v.u;
    unsigned r = (u + 0x7FFFu + ((u >> 16) & 1u)) >> 16;
    return (unsigned short)r;
}
__device__ inline float bf2f(unsigned short h) {
    union { unsigned u; float f; } v; v.u = ((unsigned)h) << 16;
    return v.f;
}

// ---------------------------------------------------------------------------
// Weight prep (see round 0): W1t [256,128] bf16, W3t [128,256] bf16 (N x K).
// ---------------------------------------------------------------------------
__global__ void prep_weights(const float* __restrict__ W1, const float* __restrict__ W2,
                             const float* __restrict__ LW,
                             unsigned short* __restrict__ W1t,
                             unsigned short* __restrict__ W3t) {
    int i = blockIdx.x * 256 + threadIdx.x;  // 0..65535
    if (i < 32768) {
        int jj = i >> 7, k = i & 127;
        float v = (jj < 128) ? W1[k * 128 + jj] : W1[(128 + k) * 128 + (jj - 128)];
        W1t[i] = f2bf(v);
    } else {
        int i2 = i - 32768;
        int n = i2 >> 8, k = i2 & 255;
        float v = (k < 128) ? W2[k * 128 + n] : LW[(k - 128) * 128 + n];
        W3t[i2] = f2bf(v);
    }
}

// feat (f32 [N,128]) -> X2 cols 128..255 (bf16, row stride 256)
__global__ void feat_to_bf16(const float* __restrict__ feat,
                             unsigned short* __restrict__ X2, int total) {
    int idx = (blockIdx.x * 256 + threadIdx.x) * 4;
    if (idx >= total) return;
    float4 v = *(const float4*)(feat + idx);
    int row = idx >> 7, col = idx & 127;
    unsigned short* o = X2 + (size_t)row * 256 + 128 + col;
    ushort4 u = make_ushort4(f2bf(v.x), f2bf(v.y), f2bf(v.z), f2bf(v.w));
    *(ushort4*)o = u;
}

// ---------------------------------------------------------------------------
// CSR build: histogram -> 3-phase exclusive scan -> scatter src ids by dst.
// ---------------------------------------------------------------------------
__global__ void hist_kernel(const int* __restrict__ dst, int* __restrict__ cnt, int E) {
    int e = blockIdx.x * 256 + threadIdx.x;
    if (e < E) atomicAdd(&cnt[dst[e]], 1);
}

// per-1024-block reduction of counts -> sums[block]
__global__ void scan_reduce(const int* __restrict__ cnt, int* __restrict__ sums, int N) {
    __shared__ int l[256];
    int t = threadIdx.x, base = blockIdx.x * 1024;
    int s = 0;
#pragma unroll
    for (int i = 0; i < 4; i++) {
        int idx = base + t * 4 + i;
        if (idx < N) s += cnt[idx];
    }
    l[t] = s;
    __syncthreads();
    for (int str = 128; str > 0; str >>= 1) {
        if (t < str) l[t] += l[t + str];
        __syncthreads();
    }
    if (t == 0) sums[blockIdx.x] = l[0];
}

// single-block exclusive scan of NB (<=256) block sums, in place
__global__ void scan_tops(int* __restrict__ sums, int NB) {
    __shared__ int l[256];
    int t = threadIdx.x;
    int orig = (t < NB) ? sums[t] : 0;
    l[t] = orig;
    __syncthreads();
    for (int off = 1; off < 256; off <<= 1) {
        int v = (t >= off) ? l[t - off] : 0;
        __syncthreads();
        l[t] += v;
        __syncthreads();
    }
    if (t < NB) sums[t] = l[t] - orig;
}

// final: per-element exclusive offsets (off) + scatter cursors (cur)
__global__ void scan_final(const int* __restrict__ cnt, const int* __restrict__ sums,
                           int* __restrict__ off, int* __restrict__ cur, int N) {
    __shared__ int l[256];
    int t = threadIdx.x, base = blockIdx.x * 1024;
    int v[4];
    int s = 0;
#pragma unroll
    for (int i = 0; i < 4; i++) {
        int idx = base + t * 4 + i;
        v[i] = (idx < N) ? cnt[idx] : 0;
        s += v[i];
    }
    int orig = s;
    l[t] = s;
    __syncthreads();
    for (int o = 1; o < 256; o <<= 1) {
        int x = (t >= o) ? l[t - o] : 0;
        __syncthreads();
        l[t] += x;
        __syncthreads();
    }
    int excl = l[t] - orig + sums[blockIdx.x];
#pragma unroll
    for (int i = 0; i < 4; i++) {
        int idx = base + t * 4 + i;
        if (idx < N) { off[idx] = excl; cur[idx] = excl; }
        excl += v[i];
    }
}

__global__ void scatter_kernel(const int* __restrict__ src, const int* __restrict__ dst,
                               int* __restrict__ cur, int* __restrict__ eSrc, int E) {
    int e = blockIdx.x * 256 + threadIdx.x;
    if (e < E) {
        int d = dst[e];
        int pos = atomicAdd(&cur[d], 1);
        eSrc[pos] = src[e];
    }
}

// ---------------------------------------------------------------------------
// Gather: one wave per dst node. Lane owns 2 channels (ushort2 of A row).
// acc += relu(A[src] + B[dst]) over the node's edge segment, registers only.
// Writes X2 cols 0..127 directly as bf16 (zero for isolated nodes).
// ---------------------------------------------------------------------------
__global__ __launch_bounds__(256) void gather_kernel(
    const unsigned short* __restrict__ AB, const int* __restrict__ off,
    const int* __restrict__ cnt, const int* __restrict__ eSrc,
    unsigned short* __restrict__ X2, int N) {
    int wid = (blockIdx.x * 256 + threadIdx.x) >> 6;  // node id
    int lane = threadIdx.x & 63;
    if (wid >= N) return;
    int start = off[wid], num = cnt[wid];
    const unsigned short* brow = AB + (size_t)wid * 256 + 128 + lane * 2;
    ushort2 bv = *(const ushort2*)brow;
    float b0 = bf2f(bv.x), b1 = bf2f(bv.y);
    float a0 = 0.f, a1 = 0.f;

    for (int j0 = 0; j0 < num; j0 += 64) {
        int myIdx = j0 + lane;
        int mySrc = (myIdx < num) ? eSrc[start + myIdx] : 0;
        int lim = min(64, num - j0);
        int j = 0;
        for (; j + 4 <= lim; j += 4) {
            int s0 = __shfl(mySrc, j);
            int s1 = __shfl(mySrc, j + 1);
            int s2 = __shfl(mySrc, j + 2);
            int s3 = __shfl(mySrc, j + 3);
            ushort2 v0 = *(const ushort2*)(AB + (size_t)s0 * 256 + lane * 2);
            ushort2 v1 = *(const ushort2*)(AB + (size_t)s1 * 256 + lane * 2);
            ushort2 v2 = *(const ushort2*)(AB + (size_t)s2 * 256 + lane * 2);
            ushort2 v3 = *(const ushort2*)(AB + (size_t)s3 * 256 + lane * 2);
            float x;
            x = bf2f(v0.x) + b0; a0 += fmaxf(x, 0.f);
            x = bf2f(v0.y) + b1; a1 += fmaxf(x, 0.f);
            x = bf2f(v1.x) + b0; a0 += fmaxf(x, 0.f);
            x = bf2f(v1.y) + b1; a1 += fmaxf(x, 0.f);
            x = bf2f(v2.x) + b0; a0 += fmaxf(x, 0.f);
            x = bf2f(v2.y) + b1; a1 += fmaxf(x, 0.f);
            x = bf2f(v3.x) + b0; a0 += fmaxf(x, 0.f);
            x = bf2f(v3.y) + b1; a1 += fmaxf(x, 0.f);
        }
        for (; j < lim; j++) {
            int s = __shfl(mySrc, j);
            ushort2 v = *(const ushort2*)(AB + (size_t)s * 256 + lane * 2);
            float x;
            x = bf2f(v.x) + b0; a0 += fmaxf(x, 0.f);
            x = bf2f(v.y) + b1; a1 += fmaxf(x, 0.f);
        }
    }
    unsigned short* orow = X2 + (size_t)wid * 256 + lane * 2;
    *(ushort2*)orow = make_ushort2(f2bf(a0), f2bf(a1));
}

// ---------------------------------------------------------------------------
// 128x128-tile bf16 MFMA GEMM (round 0, unchanged).
// ---------------------------------------------------------------------------
template <bool OUT_BF16>
__global__ __launch_bounds__(256) void gemm128(
    const unsigned short* __restrict__ A, int lda,
    const unsigned short* __restrict__ Bt, int ldb, int nRowsB,
    void* __restrict__ Cout, int ldc,
    const float* __restrict__ bias, int M, int K) {
    __shared__ unsigned short As[128 * 128];
    __shared__ unsigned short Bs[128 * 128];
    const int tid = threadIdx.x;
    const int m0 = blockIdx.x * 128;
    const int n0 = blockIdx.y * 128;
    const int lane = tid & 63;
    const int w = tid >> 6;
    const int wr = w >> 1, wc = w & 1;
    const int q = lane >> 4, ln = lane & 15;

    f32x4 acc[4][4];
#pragma unroll
    for (int i = 0; i < 4; i++)
#pragma unroll
        for (int j = 0; j < 4; j++) acc[i][j] = (f32x4)0.f;

    for (int kk = 0; kk < K; kk += 128) {
#pragma unroll
        for (int i = 0; i < 8; i++) {
            int id = i * 256 + tid;
            int r = id >> 4, b = id & 15;
            ushort8v v = (ushort8v)(unsigned short)0;
            int gr = m0 + r;
            if (gr < M) v = *(const ushort8v*)(A + (size_t)gr * lda + kk + b * 8);
            *(ushort8v*)(As + r * 128 + ((b ^ (r & 15)) * 8)) = v;
        }
#pragma unroll
        for (int i = 0; i < 8; i++) {
            int id = i * 256 + tid;
            int r = id >> 4, b = id & 15;
            ushort8v v = (ushort8v)(unsigned short)0;
            int gr = n0 + r;
            if (gr < nRowsB) v = *(const ushort8v*)(Bt + (size_t)gr * ldb + kk + b * 8);
            *(ushort8v*)(Bs + r * 128 + ((b ^ (r & 15)) * 8)) = v;
        }
        __syncthreads();
#pragma unroll
        for (int ks = 0; ks < 4; ks++) {
            short8v af[4], bfv[4];
#pragma unroll
            for (int ti = 0; ti < 4; ti++) {
                int m = wr * 64 + ti * 16 + ln;
                int blk = (ks * 4 + q) ^ (m & 15);
                af[ti] = *(const short8v*)(As + m * 128 + blk * 8);
            }
#pragma unroll
            for (int tj = 0; tj < 4; tj++) {
                int n = wc * 64 + tj * 16 + ln;
                int blk = (ks * 4 + q) ^ (n & 15);
                bfv[tj] = *(const short8v*)(Bs + n * 128 + blk * 8);
            }
#pragma unroll
            for (int ti = 0; ti < 4; ti++)
#pragma unroll
                for (int tj = 0; tj < 4; tj++)
                    acc[ti][tj] = __builtin_amdgcn_mfma_f32_16x16x32_bf16(
                        af[ti], bfv[tj], acc[ti][tj], 0, 0, 0);
        }
        __syncthreads();
    }

#pragma unroll
    for (int ti = 0; ti < 4; ti++) {
        int rowb = m0 + wr * 64 + ti * 16 + q * 4;
#pragma unroll
        for (int tj = 0; tj < 4; tj++) {
            int col = n0 + wc * 64 + tj * 16 + ln;
            f32x4 c = acc[ti][tj];
            float bv = 0.f;
            if (!OUT_BF16 && bias) bv = bias[col];
#pragma unroll
            for (int r = 0; r < 4; r++) {
                int row = rowb + r;
                if (row < M) {
                    if (OUT_BF16)
                        ((unsigned short*)Cout)[(size_t)row * ldc + col] = f2bf(c[r]);
                    else
                        ((float*)Cout)[(size_t)row * ldc + col] = c[r] + bv;
                }
            }
        }
    }
}

// ---------------------------------------------------------------------------
extern "C" void kernel_launch(void* const* d_in, const int* in_sizes, int n_in,
                              void* d_out, int out_size, void* d_ws, size_t ws_size,
                              hipStream_t stream) {
    const float* feat = (const float*)d_in[0];
    const int* src = (const int*)d_in[1];
    const int* dst = (const int*)d_in[2];
    const float* W1 = (const float*)d_in[3];
    const float* W2 = (const float*)d_in[4];
    const float* LW = (const float*)d_in[5];
    const float* bias = (const float*)d_in[6];
    float* out = (float*)d_out;

    const int N = in_sizes[0] / 128;  // 50000
    const int E = in_sizes[1];        // 800000

    char* ws = (char*)d_ws;
    unsigned short* X2 = (unsigned short*)ws;          // [N,256] bf16: 0-127 = S', 128-255 = feat
    size_t off_b = (size_t)N * 256 * 2;
    unsigned short* AB = (unsigned short*)(ws + off_b);  // [N,256] bf16: A | B
    off_b += (size_t)N * 256 * 2;
    unsigned short* W1t = (unsigned short*)(ws + off_b);
    off_b += (size_t)256 * 128 * 2;
    unsigned short* W3t = (unsigned short*)(ws + off_b);
    off_b += (size_t)128 * 256 * 2;
    int* cnt = (int*)(ws + off_b);   off_b += (size_t)N * 4;
    int* offs = (int*)(ws + off_b);  off_b += (size_t)N * 4;
    int* cur = (int*)(ws + off_b);   off_b += (size_t)N * 4;
    int* sums = (int*)(ws + off_b);  off_b += 256 * 4;
    int* eSrc = (int*)(ws + off_b);  off_b += (size_t)E * 4;

    const int NB = (N + 1023) / 1024;  // scan blocks

    // --- CSR build (independent of GEMM chain; same stream serializes) ---
    hipMemsetAsync(cnt, 0, (size_t)N * 4, stream);
    hist_kernel<<<(E + 255) / 256, 256, 0, stream>>>(dst, cnt, E);
    scan_reduce<<<NB, 256, 0, stream>>>(cnt, sums, N);
    scan_tops<<<1, 256, 0, stream>>>(sums, NB);
    scan_final<<<NB, 256, 0, stream>>>(cnt, sums, offs, cur, N);
    scatter_kernel<<<(E + 255) / 256, 256, 0, stream>>>(src, dst, cur, eSrc, E);

    // --- dense chain ---
    prep_weights<<<256, 256, 0, stream>>>(W1, W2, LW, W1t, W3t);
    int totalF = N * 128;
    int cvtBlocks = (totalF / 4 + 255) / 256;
    feat_to_bf16<<<cvtBlocks, 256, 0, stream>>>(feat, X2, totalF);

    dim3 g1((N + 127) / 128, 2);
    gemm128<true><<<g1, 256, 0, stream>>>(X2 + 128, 256, W1t, 128, 256,
                                          (void*)AB, 256, nullptr, N, 128);

    // --- per-node gather (no atomics), writes X2 cols 0..127 bf16 ---
    gather_kernel<<<(N + 3) / 4, 256, 0, stream>>>(AB, offs, cnt, eSrc, X2, N);

    dim3 g2((N + 127) / 128, 1);
    gemm128<false><<<g2, 256, 0, stream>>>(X2, 256, W3t, 256, 128,
                                           (void*)out, 128, bias, N, 256);
}